// Round 5
// baseline (3364.491 us; speedup 1.0000x reference)
//
#include <hip/hip_runtime.h>

#define BATCH 4
#define NPTS  2048
#define DIM   16
#define REGEPS 0.01f
#define DECAYF 0.9f
#define MINUPD 0.01f
#define MAXIT  50
#define LOGN   7.62461898616f   // ln(2048)
#define L2E    1.44269504089f   // log2(e)
#define LN2    0.69314718056f

// ---- workspace layout (units of 4 bytes) ----
#define OFF_SX    0
#define OFF_SQ    (BATCH*NPTS*DIM)            // 131072
#define OFF_F     (OFF_SQ + BATCH*NPTS)       // 139264
#define OFF_G     (OFF_F + BATCH*NPTS)        // 147456
#define OFF_MEAN  (OFF_G + BATCH*NPTS)        // 155648
#define OFF_SCALE (OFF_MEAN + BATCH*DIM)      // 155712
#define OFF_EPS0  (OFF_SCALE + BATCH)         // 155716
// per-batch sync region: 64 floats (256B) each, 256B-aligned base.
//   +0  : arrive counter (int, RMW by 64 blocks)     } line 0
//   +2,3: upd dual slots (uint atomicMax)            } line 0
//   +32 : epoch flag (int, 1 writer, 63 pollers)     } line 1
#define OFF_SYNC  155776                      // 623104 B, 256B aligned

// ============================================================
// Preprocess (proven): mean/std/scale, sx, sq, extent->eps0,
// zero f/g, init sync region.  grid = BATCH x 256
// ============================================================
__global__ __launch_bounds__(256) void ot_preproc(const float* __restrict__ state,
                                                  float* __restrict__ ws) {
  const int b = blockIdx.x;
  const int tid = threadIdx.x;
  __shared__ float s_sum[16][17];
  __shared__ float s_sq[16][17];
  __shared__ float s_mean[16];
  __shared__ float s_red[8];
  __shared__ float s_scale_sh;

  const float* st = state + b * NPTS * DIM;
  const int d = tid & 15, grp = tid >> 4;
  float sm = 0.f, s2 = 0.f;
  for (int n = grp; n < NPTS; n += 16) {
    float x = st[n * DIM + d];
    sm += x; s2 += x * x;
  }
  s_sum[grp][d] = sm; s_sq[grp][d] = s2;
  __syncthreads();
  if (tid < 16) {
    float S = 0.f, Q = 0.f;
    for (int g2 = 0; g2 < 16; ++g2) { S += s_sum[g2][tid]; Q += s_sq[g2][tid]; }
    float mean = S * (1.0f / NPTS);
    float var  = fmaxf(Q * (1.0f / NPTS) - mean * mean, 0.f);
    float sd   = sqrtf(var);
    s_mean[tid] = mean;
    ws[OFF_MEAN + b * DIM + tid] = mean;
    s_sum[0][tid] = sd;
  }
  __syncthreads();
  if (tid == 0) {
    float dm = 0.f;
    for (int d2 = 0; d2 < 16; ++d2) dm = fmaxf(dm, s_sum[0][d2]);
    if (dm == 0.f) dm = 1.f;
    float scale = dm * 4.0f;          // * sqrt(D=16)
    s_scale_sh = scale;
    ws[OFF_SCALE + b] = scale;
  }
  __syncthreads();

  const float inv_scale = 1.0f / s_scale_sh;
  float vmin = 3.0e38f, vmax = -3.0e38f;
  float* sx = ws + OFF_SX + b * NPTS * DIM;
  float* sq = ws + OFF_SQ + b * NPTS;
  for (int n = tid; n < NPTS; n += 256) {
    const float4* rp = (const float4*)(st + n * DIM);
    float4 xs0 = rp[0], xs1 = rp[1], xs2 = rp[2], xs3 = rp[3];
    float xv[16] = {xs0.x,xs0.y,xs0.z,xs0.w, xs1.x,xs1.y,xs1.z,xs1.w,
                    xs2.x,xs2.y,xs2.z,xs2.w, xs3.x,xs3.y,xs3.z,xs3.w};
    float ov[16];
    float q = 0.f;
    #pragma unroll
    for (int e = 0; e < 16; ++e) {
      float v = (xv[e] - s_mean[e]) * inv_scale;
      ov[e] = v; q += v * v;
      vmin = fminf(vmin, v); vmax = fmaxf(vmax, v);
    }
    float4* op = (float4*)(sx + n * DIM);
    op[0] = make_float4(ov[0],ov[1],ov[2],ov[3]);
    op[1] = make_float4(ov[4],ov[5],ov[6],ov[7]);
    op[2] = make_float4(ov[8],ov[9],ov[10],ov[11]);
    op[3] = make_float4(ov[12],ov[13],ov[14],ov[15]);
    sq[n] = q;
  }
  float* fv = ws + OFF_F + b * NPTS;
  float* gv = ws + OFF_G + b * NPTS;
  for (int n = tid; n < NPTS; n += 256) { fv[n] = 0.f; gv[n] = 0.f; }
  #pragma unroll
  for (int off = 32; off > 0; off >>= 1) {
    vmin = fminf(vmin, __shfl_xor(vmin, off));
    vmax = fmaxf(vmax, __shfl_xor(vmax, off));
  }
  const int wv = tid >> 6, ln = tid & 63;
  if (ln == 0) { s_red[wv] = vmin; s_red[4 + wv] = vmax; }
  __syncthreads();
  if (tid == 0) {
    float mn = fminf(fminf(s_red[0], s_red[1]), fminf(s_red[2], s_red[3]));
    float mx = fmaxf(fmaxf(s_red[4], s_red[5]), fmaxf(s_red[6], s_red[7]));
    ws[OFF_EPS0 + b] = mx - mn;
    int* sy = (int*)ws + OFF_SYNC + b * 64;
    sy[0] = 0;                       // arrive
    ((unsigned int*)sy)[2] = 0u;     // upd slot 0
    ((unsigned int*)sy)[3] = 0u;     // upd slot 1
    sy[32] = 0;                      // epoch
  }
}

// ============================================================
// Coherent (cross-XCD) 16B load: bypass L1/L2.
// ============================================================
__device__ __forceinline__ float4 load_f4_coherent(const float* p) {
  float4 v;
  asm volatile("global_load_dwordx4 %0, %1, off sc0 sc1\n\t"
               "s_waitcnt vmcnt(0)"
               : "=v"(v) : "v"(p) : "memory");
  return v;
}

// ============================================================
// Epoch-broadcast barrier among the 64 blocks of one batch (proven R3).
// ============================================================
__device__ __forceinline__ void batch_barrier(int* sy, int ph) {
  __syncthreads();
  if (threadIdx.x == 0) {
    int* arrive = sy;
    int* epoch  = sy + 32;
    const int old = __hip_atomic_fetch_add(arrive, 1, __ATOMIC_ACQ_REL,
                                           __HIP_MEMORY_SCOPE_AGENT);
    if (old == 64 * ph - 1) {
      __hip_atomic_store(epoch, ph, __ATOMIC_RELEASE, __HIP_MEMORY_SCOPE_AGENT);
    } else {
      while (__hip_atomic_load(epoch, __ATOMIC_RELAXED, __HIP_MEMORY_SCOPE_AGENT) < ph)
        __builtin_amdgcn_s_sleep(2);
      (void)__hip_atomic_load(epoch, __ATOMIC_ACQUIRE, __HIP_MEMORY_SCOPE_AGENT);
    }
  }
  __syncthreads();
}

__device__ __forceinline__ float rfl(float v) {
  return __int_as_float(__builtin_amdgcn_readfirstlane(__float_as_int(v)));
}

// Half-range LSE sweep: 4 chunks of 256 j starting at jbase.
// sxr = wave-uniform (SGPR) row operands 2*L2E*sx_i; acc_dot scaled by
// inv_eps at the end (one fma), a2 already carries L2E/eps.
__device__ __forceinline__ void lse_sweep_half(const float* __restrict__ s_xt,
                                               const float* __restrict__ s_a2,
                                               const float (&sxr)[4][16],
                                               float inv_eps, int jbase, int l,
                                               float (&M)[4], float (&S)[4]) {
  #pragma unroll
  for (int r = 0; r < 4; ++r) { M[r] = -3.0e38f; S[r] = 0.0f; }
  for (int c = 0; c < 4; ++c) {
    const int jb = jbase + c * 256 + 4 * l;
    const float4 av = *(const float4*)(s_a2 + jb);
    float acc[4][4];
    {
      const float4 xj = *(const float4*)(s_xt + jb);   // dd = 0
      #pragma unroll
      for (int r = 0; r < 4; ++r) {
        acc[r][0] = sxr[r][0] * xj.x;
        acc[r][1] = sxr[r][0] * xj.y;
        acc[r][2] = sxr[r][0] * xj.z;
        acc[r][3] = sxr[r][0] * xj.w;
      }
    }
    #pragma unroll
    for (int dd = 1; dd < 16; ++dd) {
      const float4 xj = *(const float4*)(s_xt + dd * 2048 + jb);
      #pragma unroll
      for (int r = 0; r < 4; ++r) {
        acc[r][0] = fmaf(sxr[r][dd], xj.x, acc[r][0]);
        acc[r][1] = fmaf(sxr[r][dd], xj.y, acc[r][1]);
        acc[r][2] = fmaf(sxr[r][dd], xj.z, acc[r][2]);
        acc[r][3] = fmaf(sxr[r][dd], xj.w, acc[r][3]);
      }
    }
    #pragma unroll
    for (int r = 0; r < 4; ++r) {
      const float v0 = fmaf(acc[r][0], inv_eps, av.x);
      const float v1 = fmaf(acc[r][1], inv_eps, av.y);
      const float v2 = fmaf(acc[r][2], inv_eps, av.z);
      const float v3 = fmaf(acc[r][3], inv_eps, av.w);
      const float cmx = fmaxf(fmaxf(v0, v1), fmaxf(v2, v3));
      const float nm = fmaxf(M[r], cmx);
      const float e0 = exp2f(M[r] - nm);
      const float sa = exp2f(v0-nm) + exp2f(v1-nm) + exp2f(v2-nm) + exp2f(v3-nm);
      S[r] = fmaf(S[r], e0, sa);
      M[r] = nm;
    }
  }
}

__device__ __forceinline__ void lse_butterfly(float (&M)[4], float (&S)[4]) {
  #pragma unroll
  for (int off = 1; off < 64; off <<= 1) {
    #pragma unroll
    for (int r = 0; r < 4; ++r) {
      const float om = __shfl_xor(M[r], off);
      const float os = __shfl_xor(S[r], off);
      const float nm = fmaxf(M[r], om);
      S[r] = S[r] * exp2f(M[r] - nm) + os * exp2f(om - nm);
      M[r] = nm;
    }
  }
}

// ============================================================
// Persistent Sinkhorn. 256 blocks x 1024 threads (16 waves), 1 block/CU.
// Wave pair (w, w+8) shares 4 rows, splits j-range in halves.
// LDS: sxT[16][2048] + a2[2048] + wl2[2048] + mrg[64].
// ============================================================
__global__ __launch_bounds__(1024, 4) void ot_sinkhorn(float* __restrict__ ws,
                                                       const float* __restrict__ wlog) {
  extern __shared__ float lds[];
  float* s_xt  = lds;                 // [16][2048]
  float* s_a2  = lds + 16 * 2048;     // [2048]
  float* s_wl2 = s_a2 + 2048;         // [2048]
  float* s_mrg = s_wl2 + 2048;        // [64]

  const int bid = blockIdx.x;
  const int b  = bid >> 6;            // 64 blocks / batch
  const int rb = bid & 63;
  const int tid = threadIdx.x;
  const int w = tid >> 6, l = tid & 63;
  const int wlo = w & 7;              // row group 0..7
  const int jbase = (w >> 3) * 1024;  // j half

  const float* __restrict__ sx = ws + OFF_SX + b * NPTS * DIM;
  const float* __restrict__ sq = ws + OFF_SQ + b * NPTS;
  float* fv = ws + OFF_F + b * NPTS;
  float* gv = ws + OFF_G + b * NPTS;
  const float* __restrict__ wl = wlog + b * NPTS;
  int* sy = (int*)ws + OFF_SYNC + b * 64;
  unsigned int* up2 = (unsigned int*)sy + 2;

  // ---- one-time LDS staging: transposed sx + wl*log2e
  for (int j = tid; j < NPTS; j += 1024) {
    const float4* rp = (const float4*)(sx + j * DIM);
    float4 t0 = rp[0], t1 = rp[1], t2 = rp[2], t3 = rp[3];
    s_xt[ 0*2048+j]=t0.x; s_xt[ 1*2048+j]=t0.y; s_xt[ 2*2048+j]=t0.z; s_xt[ 3*2048+j]=t0.w;
    s_xt[ 4*2048+j]=t1.x; s_xt[ 5*2048+j]=t1.y; s_xt[ 6*2048+j]=t1.z; s_xt[ 7*2048+j]=t1.w;
    s_xt[ 8*2048+j]=t2.x; s_xt[ 9*2048+j]=t2.y; s_xt[10*2048+j]=t2.z; s_xt[11*2048+j]=t2.w;
    s_xt[12*2048+j]=t3.x; s_xt[13*2048+j]=t3.y; s_xt[14*2048+j]=t3.z; s_xt[15*2048+j]=t3.w;
    s_wl2[j] = wl[j] * L2E;
  }
  // ---- own rows, constant 2*L2E*sx, forced into SGPRs (wave-uniform)
  const int row0 = rb * 32 + wlo * 4;
  float sxr[4][16];
  #pragma unroll
  for (int r = 0; r < 4; ++r) {
    const float4* rp = (const float4*)(sx + (row0 + r) * DIM);
    const float4 t0 = rp[0], t1 = rp[1], t2 = rp[2], t3 = rp[3];
    const float c2 = 2.0f * L2E;
    sxr[r][0]=rfl(t0.x*c2);  sxr[r][1]=rfl(t0.y*c2);  sxr[r][2]=rfl(t0.z*c2);  sxr[r][3]=rfl(t0.w*c2);
    sxr[r][4]=rfl(t1.x*c2);  sxr[r][5]=rfl(t1.y*c2);  sxr[r][6]=rfl(t1.z*c2);  sxr[r][7]=rfl(t1.w*c2);
    sxr[r][8]=rfl(t2.x*c2);  sxr[r][9]=rfl(t2.y*c2);  sxr[r][10]=rfl(t2.z*c2); sxr[r][11]=rfl(t2.w*c2);
    sxr[r][12]=rfl(t3.x*c2); sxr[r][13]=rfl(t3.y*c2); sxr[r][14]=rfl(t3.z*c2); sxr[r][15]=rfl(t3.w*c2);
  }
  float eps = ws[OFF_EPS0 + b];
  __syncthreads();

  int ph = 0;
  for (int it = 0; it < MAXIT; ++it) {
    const float le      = L2E / eps;
    const float eln2    = eps * LN2;
    const float inv_eps = 1.0f / eps;

    // ================= F phase (src = g) =================
    if (tid < 512) {
      const int j4 = tid * 4;
      const float4 gj = load_f4_coherent(gv + j4);
      const float4 qj = *(const float4*)(sq + j4);
      *(float4*)(s_a2 + j4) = make_float4((gj.x - qj.x) * le, (gj.y - qj.y) * le,
                                          (gj.z - qj.z) * le, (gj.w - qj.w) * le);
    }
    __syncthreads();
    {
      float M[4], S[4];
      lse_sweep_half(s_xt, s_a2, sxr, inv_eps, jbase, l, M, S);
      lse_butterfly(M, S);
      if (w >= 8 && l < 4) {
        const float Mr = (l==0)?M[0]:(l==1)?M[1]:(l==2)?M[2]:M[3];
        const float Sr = (l==0)?S[0]:(l==1)?S[1]:(l==2)?S[2]:S[3];
        s_mrg[(wlo * 4 + l) * 2]     = Mr;
        s_mrg[(wlo * 4 + l) * 2 + 1] = Sr;
      }
      __syncthreads();
      if (w < 8 && l < 4) {
        const float M1 = (l==0)?M[0]:(l==1)?M[1]:(l==2)?M[2]:M[3];
        const float S1 = (l==0)?S[0]:(l==1)?S[1]:(l==2)?S[2]:S[3];
        const float M2 = s_mrg[(wlo * 4 + l) * 2];
        const float S2 = s_mrg[(wlo * 4 + l) * 2 + 1];
        const float nm = fmaxf(M1, M2);
        const float St = S1 * exp2f(M1 - nm) + S2 * exp2f(M2 - nm);
        const int i = row0 + l;
        const float qi = sq[i];
        const float fnew = fmaf(eps, LOGN, qi) - eln2 * (nm + log2f(St));
        const float old = __hip_atomic_load(fv + i, __ATOMIC_RELAXED, __HIP_MEMORY_SCOPE_AGENT);
        __hip_atomic_store(fv + i, fnew, __ATOMIC_RELEASE, __HIP_MEMORY_SCOPE_AGENT);
        __hip_atomic_fetch_max(up2 + (it & 1), __float_as_uint(fabsf(fnew - old)),
                               __ATOMIC_RELAXED, __HIP_MEMORY_SCOPE_AGENT);
      }
    }
    ++ph; batch_barrier(sy, ph);

    // ================= G phase (src = f, + log_a) =================
    if (rb == 0 && tid == 0)
      __hip_atomic_store(up2 + ((it + 1) & 1), 0u, __ATOMIC_RELAXED, __HIP_MEMORY_SCOPE_AGENT);
    if (tid < 512) {
      const int j4 = tid * 4;
      const float4 fj = load_f4_coherent(fv + j4);
      const float4 qj = *(const float4*)(sq + j4);
      const float4 w2 = *(const float4*)(s_wl2 + j4);
      *(float4*)(s_a2 + j4) = make_float4(fmaf(fj.x - qj.x, le, w2.x), fmaf(fj.y - qj.y, le, w2.y),
                                          fmaf(fj.z - qj.z, le, w2.z), fmaf(fj.w - qj.w, le, w2.w));
    }
    __syncthreads();
    {
      float M[4], S[4];
      lse_sweep_half(s_xt, s_a2, sxr, inv_eps, jbase, l, M, S);
      lse_butterfly(M, S);
      if (w >= 8 && l < 4) {
        const float Mr = (l==0)?M[0]:(l==1)?M[1]:(l==2)?M[2]:M[3];
        const float Sr = (l==0)?S[0]:(l==1)?S[1]:(l==2)?S[2]:S[3];
        s_mrg[(wlo * 4 + l) * 2]     = Mr;
        s_mrg[(wlo * 4 + l) * 2 + 1] = Sr;
      }
      __syncthreads();
      if (w < 8 && l < 4) {
        const float M1 = (l==0)?M[0]:(l==1)?M[1]:(l==2)?M[2]:M[3];
        const float S1 = (l==0)?S[0]:(l==1)?S[1]:(l==2)?S[2]:S[3];
        const float M2 = s_mrg[(wlo * 4 + l) * 2];
        const float S2 = s_mrg[(wlo * 4 + l) * 2 + 1];
        const float nm = fmaxf(M1, M2);
        const float St = S1 * exp2f(M1 - nm) + S2 * exp2f(M2 - nm);
        const int i = row0 + l;
        const float qm = sq[i];
        const float gnew = qm - eln2 * (nm + log2f(St));
        const float old = __hip_atomic_load(gv + i, __ATOMIC_RELAXED, __HIP_MEMORY_SCOPE_AGENT);
        __hip_atomic_store(gv + i, gnew, __ATOMIC_RELEASE, __HIP_MEMORY_SCOPE_AGENT);
        __hip_atomic_fetch_max(up2 + (it & 1), __float_as_uint(fabsf(gnew - old)),
                               __ATOMIC_RELAXED, __HIP_MEMORY_SCOPE_AGENT);
      }
    }
    if (it < MAXIT - 1) {
      ++ph; batch_barrier(sy, ph);
      const unsigned uu = __hip_atomic_load(up2 + (it & 1), __ATOMIC_RELAXED, __HIP_MEMORY_SCOPE_AGENT);
      const bool conv = (__uint_as_float(uu) < MINUPD) && (eps <= REGEPS);  // eps = pre-update (ref eps2)
      if (conv) break;
      eps = fmaxf(eps * DECAYF, REGEPS);
    }
  }
}

// ============================================================
// Output (proven): new_state + uniform_log_w.
// grid = BATCH * (NPTS/8) = 1024 blocks x 256 threads.
// ============================================================
__global__ __launch_bounds__(256) void ot_out(float* __restrict__ ws,
                                              const float* __restrict__ wlog,
                                              float* __restrict__ out) {
  __shared__ float s_xt[DIM][256];
  __shared__ float s_p[256];
  __shared__ float s_q[256];
  const int bid = blockIdx.x;
  const int b  = bid >> 8;
  const int rb = bid & 255;
  const int tid = threadIdx.x;
  const int w = tid >> 6, l = tid & 63;
  const float invR = 1.0f / REGEPS;

  const float* __restrict__ sx = ws + OFF_SX + b * NPTS * DIM;
  const float* __restrict__ sq = ws + OFF_SQ + b * NPTS;
  const float* __restrict__ fv = ws + OFF_F + b * NPTS;
  const float* __restrict__ gv = ws + OFF_G + b * NPTS;
  const float* __restrict__ wl = wlog + b * NPTS;

  const int row0 = rb * 8 + w * 2;
  float sxm[2][DIM], cm2[2], qm[2], acc[2][DIM], accT[2];
  #pragma unroll
  for (int r = 0; r < 2; ++r) {
    const int mrow = row0 + r;
    cm2[r] = sq[mrow];
    qm[r]  = gv[mrow] * invR;
    const float4* rp = (const float4*)(sx + mrow * DIM);
    #pragma unroll
    for (int c4 = 0; c4 < 4; ++c4) {
      float4 t = rp[c4];
      sxm[r][c4*4+0] = -2.0f * t.x; sxm[r][c4*4+1] = -2.0f * t.y;
      sxm[r][c4*4+2] = -2.0f * t.z; sxm[r][c4*4+3] = -2.0f * t.w;
    }
    #pragma unroll
    for (int dd = 0; dd < DIM; ++dd) acc[r][dd] = 0.0f;
    accT[r] = 0.0f;
  }

  for (int k = 0; k < NPTS / 256; ++k) {
    __syncthreads();
    {
      const int n = k * 256 + tid;
      const float4* rp = (const float4*)(sx + n * DIM);
      float4 t0 = rp[0], t1 = rp[1], t2 = rp[2], t3 = rp[3];
      s_xt[0][tid]=t0.x;  s_xt[1][tid]=t0.y;  s_xt[2][tid]=t0.z;  s_xt[3][tid]=t0.w;
      s_xt[4][tid]=t1.x;  s_xt[5][tid]=t1.y;  s_xt[6][tid]=t1.z;  s_xt[7][tid]=t1.w;
      s_xt[8][tid]=t2.x;  s_xt[9][tid]=t2.y;  s_xt[10][tid]=t2.z; s_xt[11][tid]=t2.w;
      s_xt[12][tid]=t3.x; s_xt[13][tid]=t3.y; s_xt[14][tid]=t3.z; s_xt[15][tid]=t3.w;
      s_q[tid] = sq[n];
      s_p[tid] = wl[n] - LOGN + fv[n] * invR;
    }
    __syncthreads();
    const float4 pv = *(const float4*)&s_p[4 * l];
    const float4 qv = *(const float4*)&s_q[4 * l];
    float a2[2][4];
    #pragma unroll
    for (int r = 0; r < 2; ++r) {
      a2[r][0] = cm2[r] + qv.x; a2[r][1] = cm2[r] + qv.y;
      a2[r][2] = cm2[r] + qv.z; a2[r][3] = cm2[r] + qv.w;
    }
    #pragma unroll
    for (int dd = 0; dd < DIM; ++dd) {
      const float4 xj = *(const float4*)&s_xt[dd][4 * l];
      #pragma unroll
      for (int r = 0; r < 2; ++r) {
        const float xr = sxm[r][dd];
        a2[r][0] = fmaf(xr, xj.x, a2[r][0]);
        a2[r][1] = fmaf(xr, xj.y, a2[r][1]);
        a2[r][2] = fmaf(xr, xj.z, a2[r][2]);
        a2[r][3] = fmaf(xr, xj.w, a2[r][3]);
      }
    }
    float T[2][4];
    #pragma unroll
    for (int r = 0; r < 2; ++r) {
      T[r][0] = __expf(fmaf(fmaxf(a2[r][0], 0.f), -invR, pv.x + qm[r]));
      T[r][1] = __expf(fmaf(fmaxf(a2[r][1], 0.f), -invR, pv.y + qm[r]));
      T[r][2] = __expf(fmaf(fmaxf(a2[r][2], 0.f), -invR, pv.z + qm[r]));
      T[r][3] = __expf(fmaf(fmaxf(a2[r][3], 0.f), -invR, pv.w + qm[r]));
      accT[r] += (T[r][0] + T[r][1]) + (T[r][2] + T[r][3]);
    }
    #pragma unroll
    for (int dd = 0; dd < DIM; ++dd) {
      const float4 xj = *(const float4*)&s_xt[dd][4 * l];
      #pragma unroll
      for (int r = 0; r < 2; ++r) {
        float t = acc[r][dd];
        t = fmaf(T[r][0], xj.x, t);
        t = fmaf(T[r][1], xj.y, t);
        t = fmaf(T[r][2], xj.z, t);
        t = fmaf(T[r][3], xj.w, t);
        acc[r][dd] = t;
      }
    }
  }
  #pragma unroll
  for (int off = 1; off < 64; off <<= 1) {
    #pragma unroll
    for (int r = 0; r < 2; ++r) {
      #pragma unroll
      for (int dd = 0; dd < DIM; ++dd) acc[r][dd] += __shfl_xor(acc[r][dd], off);
      accT[r] += __shfl_xor(accT[r], off);
    }
  }
  if (l == 0) {
    const float scale = ws[OFF_SCALE + b];
    const float* mean = ws + OFF_MEAN + b * DIM;
    #pragma unroll
    for (int r = 0; r < 2; ++r) {
      const int mrow = row0 + r;
      float ov[16];
      #pragma unroll
      for (int dd = 0; dd < DIM; ++dd)
        ov[dd] = (float)NPTS * fmaf(scale, acc[r][dd], mean[dd] * accT[r]);
      float4* op = (float4*)(out + (b * NPTS + mrow) * DIM);
      op[0] = make_float4(ov[0],ov[1],ov[2],ov[3]);
      op[1] = make_float4(ov[4],ov[5],ov[6],ov[7]);
      op[2] = make_float4(ov[8],ov[9],ov[10],ov[11]);
      op[3] = make_float4(ov[12],ov[13],ov[14],ov[15]);
    }
  }
  if (tid < 8) out[BATCH * NPTS * DIM + b * NPTS + rb * 8 + tid] = -LOGN;
}

extern "C" void kernel_launch(void* const* d_in, const int* in_sizes, int n_in,
                              void* d_out, int out_size, void* d_ws, size_t ws_size,
                              hipStream_t stream) {
  (void)in_sizes; (void)n_in; (void)out_size; (void)ws_size;
  const float* state  = (const float*)d_in[0];
  const float* weight = (const float*)d_in[1];
  float* out = (float*)d_out;
  float* ws  = (float*)d_ws;

  ot_preproc<<<dim3(BATCH), dim3(256), 0, stream>>>(state, ws);

  const unsigned int dynLds = 147712;  // sxT 128K + a2 8K + wl2 8K + mrg 256B
  hipFuncSetAttribute((const void*)ot_sinkhorn,
                      hipFuncAttributeMaxDynamicSharedMemorySize, (int)dynLds);
  // 256 blocks x 1024 thr (16 waves), 144KB LDS -> 1 block/CU, all co-resident
  hipLaunchKernelGGL(ot_sinkhorn, dim3(256), dim3(1024), dynLds, stream, ws, weight);

  ot_out<<<dim3(BATCH * NPTS / 8), dim3(256), 0, stream>>>(ws, weight, out);
}